// Round 6
// baseline (424.176 us; speedup 1.0000x reference)
//
#include <hip/hip_runtime.h>
#include <math.h>

#define HD    256
#define NHEAD 4
#define NSEG  1024
#define NRB   3125                                  // 400000/128 row blocks

typedef short bf16x8 __attribute__((ext_vector_type(8)));
typedef float f32x16 __attribute__((ext_vector_type(16)));

__device__ __forceinline__ float tanh_fast(float v) {
    float e = __expf(2.0f * v);                    // overflow->inf, tanh->1: ok
    return 1.0f - 2.0f * __builtin_amdgcn_rcpf(e + 1.0f);
}

// split fp32 pair into packed bf16-hi word and bf16-lo word (truncation split;
// lo captures mantissa bits 9..17 -> per-product rel err ~2^-17)
__device__ __forceinline__ void split2(float a, float b, unsigned &hi, unsigned &lo) {
    unsigned ba = __float_as_uint(a), bb = __float_as_uint(b);
    unsigned ha = ba & 0xFFFF0000u, hb = bb & 0xFFFF0000u;
    float la = a - __uint_as_float(ha);
    float lb = b - __uint_as_float(hb);
    hi = (ha >> 16) | hb;
    lo = (__float_as_uint(la) >> 16) | (__float_as_uint(lb) & 0xFFFF0000u);
}

__device__ __forceinline__ void gld16(const void* g, void* l) {
    __builtin_amdgcn_global_load_lds(
        (const __attribute__((address_space(1))) void*)g,
        (__attribute__((address_space(3))) void*)l, 16, 0, 0);
}

// ---------------------------------------------------------------------------
// k0_prep: W1 (fp32 [k][c]) -> ws split-bf16 planes laid out exactly as k1's
// per-chunk LDS image: off = t*32768 + ch*16384 + pl*8192 + o*2048 + c*16 + j*4
// (t = KC=32 chunk, ch = col half, pl = hi/lo plane, o = k-oct, c = col in
//  half, j = k-pair). 256 KiB total.
// ---------------------------------------------------------------------------
__global__ __launch_bounds__(256) void k0_prep(
    const float* __restrict__ W1, char* __restrict__ ws)
{
    int g = blockIdx.x * 256 + threadIdx.x;        // 32768 threads
    int c  = g & 127;
    int j  = (g >> 7) & 3;
    int o  = (g >> 9) & 3;
    int ch = (g >> 11) & 1;
    int t  = g >> 12;
    int k   = t*32 + o*8 + 2*j;
    int col = ch*128 + c;
    float a = W1[(size_t)k * HD + col];
    float b = W1[(size_t)(k + 1) * HD + col];
    unsigned hw, lw;
    split2(a, b, hw, lw);
    size_t off = (size_t)t*32768 + ch*16384 + o*2048 + c*16 + j*4;
    *(unsigned*)(ws + off)        = hw;
    *(unsigned*)(ws + off + 8192) = lw;
}

// ---------------------------------------------------------------------------
// K1: partial logits for one 128-col half.
// 256 thr = 4 waves: rg = wid>>1 (2 x 64 rows), cg = wid&1 (2 x 64 cols).
// Wave tile 64x64 = 2rt x 2ct of 32x32 mfma -> acc = 64 AGPR (occupancy!).
// x (A) direct from global (L1/L2 absorb dup - FETCH const in R3/R4/R5).
// W via global_load_lds from pre-split ws; KC=32 double-buffered (32 KiB).
// launch_bounds(256,3): 3 waves/SIMD, 3 blocks/CU -> drains de-correlate.
// Col-half blocks write partial logits lgA (+b1,b2 terms of own cols) / lgB;
// k2/k3 sum them (no atomics -> deterministic).
// bid swizzle: both col-halves of a row-slab land on the same XCD.
// ---------------------------------------------------------------------------
#define K1_THREADS 256
#define K1_LDS 32768

__global__ __launch_bounds__(K1_THREADS, 3) void k1_mfma(
    const float* __restrict__ x, const char* __restrict__ wsW,
    const float* __restrict__ b1, const float* __restrict__ W2,
    const float* __restrict__ b2, float* __restrict__ lgA,
    float* __restrict__ lgB, int N)
{
    extern __shared__ __align__(16) char smem[];   // 2 x 16K W buffers

    const int raw = blockIdx.x;
    const int ch  = (raw >> 3) & 1;
    const int rb  = (raw >> 4) * 8 + (raw & 7);
    if (rb >= NRB) return;

    const int tid  = threadIdx.x;
    const int lane = tid & 63;
    const int lo5  = lane & 31;
    const int hi   = lane >> 5;
    const int wid  = tid >> 6;
    const int rg   = wid >> 1;                     // 0..1
    const int cg   = wid & 1;                      // 0..1
    const int blkrow = rb * 128;

    f32x16 acc[2][2];
    #pragma unroll
    for (int ct = 0; ct < 2; ++ct) {
        float b1v = b1[ch*128 + cg*64 + ct*32 + lo5];
        #pragma unroll
        for (int rt = 0; rt < 2; ++rt)
            #pragma unroll
            for (int e = 0; e < 16; ++e)
                acc[rt][ct][e] = b1v;
    }

    int rA[2];
    #pragma unroll
    for (int rt = 0; rt < 2; ++rt) {
        int r = blkrow + rg*64 + rt*32 + lo5;
        rA[rt] = r < N ? r : N - 1;                // clamp (N%128==0 anyway)
    }

    const char* gw = wsW + ch*16384 + tid*16;
    // prologue: stage chunk 0 -> buf 0
    #pragma unroll
    for (int i = 0; i < 4; ++i) gld16(gw + i*4096, smem + i*4096 + tid*16);
    __syncthreads();

    for (int t = 0; t < 8; ++t) {
        const int buf = (t & 1) * 16384;
        if (t < 7) {                               // stage next chunk (async)
            const char* src = gw + (size_t)(t+1)*32768;
            #pragma unroll
            for (int i = 0; i < 4; ++i)
                gld16(src + i*4096, smem + (buf ^ 16384) + i*4096 + tid*16);
        }
        #pragma unroll
        for (int ks = 0; ks < 2; ++ks) {
            union { unsigned u[4]; bf16x8 v; } ah[2], al[2];
            #pragma unroll
            for (int rt = 0; rt < 2; ++rt) {       // A: x direct, split in-reg
                const float* xp = x + (size_t)rA[rt]*HD + t*32 + ks*16 + hi*8;
                float4 q0 = *(const float4*)xp;
                float4 q1 = *(const float4*)(xp + 4);
                split2(q0.x, q0.y, ah[rt].u[0], al[rt].u[0]);
                split2(q0.z, q0.w, ah[rt].u[1], al[rt].u[1]);
                split2(q1.x, q1.y, ah[rt].u[2], al[rt].u[2]);
                split2(q1.z, q1.w, ah[rt].u[3], al[rt].u[3]);
            }
            bf16x8 bh[2], bl[2];
            #pragma unroll
            for (int ct = 0; ct < 2; ++ct) {
                int off = buf + (ks*2 + hi)*2048 + (cg*64 + ct*32 + lo5)*16;
                bh[ct] = *(const bf16x8*)(smem + off);
                bl[ct] = *(const bf16x8*)(smem + off + 8192);
            }
            #pragma unroll
            for (int rt = 0; rt < 2; ++rt)
                #pragma unroll
                for (int ct = 0; ct < 2; ++ct) {
                    acc[rt][ct] = __builtin_amdgcn_mfma_f32_32x32x16_bf16(ah[rt].v, bh[ct], acc[rt][ct], 0, 0, 0);
                    acc[rt][ct] = __builtin_amdgcn_mfma_f32_32x32x16_bf16(ah[rt].v, bl[ct], acc[rt][ct], 0, 0, 0);
                    acc[rt][ct] = __builtin_amdgcn_mfma_f32_32x32x16_bf16(al[rt].v, bh[ct], acc[rt][ct], 0, 0, 0);
                }
        }
        __syncthreads();                           // buf(t+1) staged
    }

    // epilogue: tanh -> h@W2 partial -> butterfly over 32-lane half
    #pragma unroll
    for (int rt = 0; rt < 2; ++rt)
        #pragma unroll
        for (int ct = 0; ct < 2; ++ct)
            #pragma unroll
            for (int e = 0; e < 16; ++e)
                acc[rt][ct][e] = tanh_fast(acc[rt][ct][e]);

    float4 w2v[2];
    #pragma unroll
    for (int ct = 0; ct < 2; ++ct)
        w2v[ct] = *(const float4*)(W2 + (size_t)(ch*128 + cg*64 + ct*32 + lo5) * NHEAD);

    float4 mine = make_float4(0.f, 0.f, 0.f, 0.f);
    #pragma unroll
    for (int rt = 0; rt < 2; ++rt) {
        #pragma unroll
        for (int e = 0; e < 16; ++e) {
            float s0 = 0.f, s1 = 0.f, s2 = 0.f, s3 = 0.f;
            #pragma unroll
            for (int ct = 0; ct < 2; ++ct) {
                float tv = acc[rt][ct][e];
                s0 = fmaf(tv, w2v[ct].x, s0);
                s1 = fmaf(tv, w2v[ct].y, s1);
                s2 = fmaf(tv, w2v[ct].z, s2);
                s3 = fmaf(tv, w2v[ct].w, s3);
            }
            #pragma unroll
            for (int o = 16; o >= 1; o >>= 1) {    // halves stay separate
                s0 += __shfl_xor(s0, o, 64);
                s1 += __shfl_xor(s1, o, 64);
                s2 += __shfl_xor(s2, o, 64);
                s3 += __shfl_xor(s3, o, 64);
            }
            if (lo5 == rt*16 + e) mine = make_float4(s0, s1, s2, s3);
        }
    }
    const int e_m = lo5 & 15, rt_m = lo5 >> 4;
    const int myrow = rg*64 + rt_m*32 + (e_m & 3) + 8*(e_m >> 2) + 4*hi;

    float (*p_lds)[128][4] = (float(*)[128][4])smem;   // [cg][row][4], 4 KiB
    *(float4*)p_lds[cg][myrow] = mine;
    __syncthreads();
    if (tid < 128) {
        int grow = blkrow + tid;
        if (grow < N) {
            float4 a0 = *(float4*)p_lds[0][tid];
            float4 a1 = *(float4*)p_lds[1][tid];
            float4 o;
            o.x = a0.x + a1.x; o.y = a0.y + a1.y;
            o.z = a0.z + a1.z; o.w = a0.w + a1.w;
            float* dst;
            if (ch == 0) {                         // lgA gets b2 folded in
                o.x += b2[0]; o.y += b2[1]; o.z += b2[2]; o.w += b2[3];
                dst = lgA;
            } else dst = lgB;
            *(float4*)(dst + (size_t)grow * NHEAD) = o;
        }
    }
}

// ---------------------------------------------------------------------------
__device__ __forceinline__ int lower_bound(const int* __restrict__ a, int n, int v) {
    int lo = 0, hi = n;
    while (lo < hi) { int m = (lo + hi) >> 1; if (a[m] < v) lo = m + 1; else hi = m; }
    return lo;
}

// ---------------------------------------------------------------------------
// K2: per-segment max & sum-of-exp of (lgA+lgB); stats -> out[b*256+0..7]
// ---------------------------------------------------------------------------
__global__ __launch_bounds__(256) void k2_seg(
    const int* __restrict__ batch, const float* __restrict__ lgA,
    const float* __restrict__ lgB, float* __restrict__ out, int N)
{
    const int b = blockIdx.x;
    const int tid = threadIdx.x;
    const int lane = tid & 63, wid = tid >> 6;
    const int start = lower_bound(batch, N, b);
    const int end   = lower_bound(batch, N, b + 1);
    const float4* la4 = (const float4*)lgA;
    const float4* lb4 = (const float4*)lgB;

    float4 mx = make_float4(-INFINITY, -INFINITY, -INFINITY, -INFINITY);
    for (int i = start + tid; i < end; i += 256) {
        float4 a = la4[i], bq = lb4[i];
        mx.x = fmaxf(mx.x, a.x + bq.x); mx.y = fmaxf(mx.y, a.y + bq.y);
        mx.z = fmaxf(mx.z, a.z + bq.z); mx.w = fmaxf(mx.w, a.w + bq.w);
    }
    #pragma unroll
    for (int ofs = 32; ofs >= 1; ofs >>= 1) {
        mx.x = fmaxf(mx.x, __shfl_xor(mx.x, ofs, 64));
        mx.y = fmaxf(mx.y, __shfl_xor(mx.y, ofs, 64));
        mx.z = fmaxf(mx.z, __shfl_xor(mx.z, ofs, 64));
        mx.w = fmaxf(mx.w, __shfl_xor(mx.w, ofs, 64));
    }
    __shared__ float4 red[4];
    if (lane == 0) red[wid] = mx;
    __syncthreads();
    float4 smax;
    smax.x = fmaxf(fmaxf(red[0].x, red[1].x), fmaxf(red[2].x, red[3].x));
    smax.y = fmaxf(fmaxf(red[0].y, red[1].y), fmaxf(red[2].y, red[3].y));
    smax.z = fmaxf(fmaxf(red[0].z, red[1].z), fmaxf(red[2].z, red[3].z));
    smax.w = fmaxf(fmaxf(red[0].w, red[1].w), fmaxf(red[2].w, red[3].w));
    __syncthreads();

    float4 sm = make_float4(0.f, 0.f, 0.f, 0.f);
    for (int i = start + tid; i < end; i += 256) {
        float4 a = la4[i], bq = lb4[i];
        sm.x += __expf(a.x + bq.x - smax.x); sm.y += __expf(a.y + bq.y - smax.y);
        sm.z += __expf(a.z + bq.z - smax.z); sm.w += __expf(a.w + bq.w - smax.w);
    }
    #pragma unroll
    for (int ofs = 32; ofs >= 1; ofs >>= 1) {
        sm.x += __shfl_xor(sm.x, ofs, 64);
        sm.y += __shfl_xor(sm.y, ofs, 64);
        sm.z += __shfl_xor(sm.z, ofs, 64);
        sm.w += __shfl_xor(sm.w, ofs, 64);
    }
    if (lane == 0) red[wid] = sm;
    __syncthreads();
    if (tid == 0) {
        float4 ssum;
        ssum.x = red[0].x + red[1].x + red[2].x + red[3].x;
        ssum.y = red[0].y + red[1].y + red[2].y + red[3].y;
        ssum.z = red[0].z + red[1].z + red[2].z + red[3].z;
        ssum.w = red[0].w + red[1].w + red[2].w + red[3].w;
        *(float4*)(out + (size_t)b * HD)     = smax;
        *(float4*)(out + (size_t)b * HD + 4) = ssum;
    }
}

// ---------------------------------------------------------------------------
// K3: attn = e/(sum+eps) (written over lgA = final attn out); z = sum attn*x;
//     graph_emb[b,:] = z @ Wt + (sum attn)*bt
// ---------------------------------------------------------------------------
__global__ __launch_bounds__(256) void k3_pool(
    const int* __restrict__ batch, const float* __restrict__ x,
    const float* __restrict__ Wt, const float* __restrict__ bt,
    const float* __restrict__ lgB, float* __restrict__ out, int N)
{
    const int b = blockIdx.x;
    const int tid = threadIdx.x;
    const int start = lower_bound(batch, N, b);
    const int end   = lower_bound(batch, N, b + 1);

    float4* at4 = (float4*)(out + (size_t)NSEG * HD);   // lgA now, attn after
    const float4* lb4 = (const float4*)lgB;

    const float4 smax = *(const float4*)(out + (size_t)b * HD);
    const float4 ssum = *(const float4*)(out + (size_t)b * HD + 4);
    float4 inv;
    inv.x = 1.0f / (ssum.x + 1e-16f); inv.y = 1.0f / (ssum.y + 1e-16f);
    inv.z = 1.0f / (ssum.z + 1e-16f); inv.w = 1.0f / (ssum.w + 1e-16f);

    float z0 = 0.f, z1 = 0.f, z2 = 0.f, z3 = 0.f;
    __shared__ float4 attn_s[256];

    for (int c0 = start; c0 < end; c0 += 256) {
        const int idx = c0 + tid;
        if (idx < end) {
            float4 l = at4[idx];
            float4 lb = lb4[idx];
            float4 a;
            a.x = __expf(l.x + lb.x - smax.x) * inv.x;
            a.y = __expf(l.y + lb.y - smax.y) * inv.y;
            a.z = __expf(l.z + lb.z - smax.z) * inv.z;
            a.w = __expf(l.w + lb.w - smax.w) * inv.w;
            at4[idx] = a;          // final attn output
            attn_s[tid] = a;
        }
        __syncthreads();
        const int cnt = min(256, end - c0);
        const float* xb = x + (size_t)c0 * HD + tid;
        #pragma unroll 4
        for (int i = 0; i < cnt; ++i) {
            float4 a = attn_s[i];
            float xv = xb[(size_t)i * HD];
            z0 = fmaf(a.x, xv, z0); z1 = fmaf(a.y, xv, z1);
            z2 = fmaf(a.z, xv, z2); z3 = fmaf(a.w, xv, z3);
        }
        __syncthreads();
    }

    __shared__ float zs[NHEAD][HD];
    zs[0][tid] = z0; zs[1][tid] = z1; zs[2][tid] = z2; zs[3][tid] = z3;
    __syncthreads();

    const int h = tid >> 6;                      // wave-uniform
    float smh, invh;
    if      (h == 0) { smh = ssum.x; invh = inv.x; }
    else if (h == 1) { smh = ssum.y; invh = inv.y; }
    else if (h == 2) { smh = ssum.z; invh = inv.z; }
    else             { smh = ssum.w; invh = inv.w; }

    float acc = smh * invh * bt[tid];            // (sum attn_h) * bt[j]
    #pragma unroll 4
    for (int k = 0; k < HD; ++k)
        acc = fmaf(zs[h][k], Wt[(size_t)k * HD + tid], acc);

    out[(size_t)b * HD + tid] = acc;             // overwrites stats stash: ok
}

// ---------------------------------------------------------------------------
extern "C" void kernel_launch(void* const* d_in, const int* in_sizes, int n_in,
                              void* d_out, int out_size, void* d_ws, size_t ws_size,
                              hipStream_t stream) {
    const float* x   = (const float*)d_in[0];
    const int*   bat = (const int*)  d_in[1];
    const float* W1  = (const float*)d_in[2];
    const float* b1  = (const float*)d_in[3];
    const float* W2  = (const float*)d_in[4];
    const float* b2  = (const float*)d_in[5];
    const float* Wt  = (const float*)d_in[6];
    const float* bt  = (const float*)d_in[7];
    float* out = (float*)d_out;
    const int N = in_sizes[0] / HD;

    float* lgA = out + (size_t)NSEG * HD;          // attn region of d_out
    char*  wsW = (char*)d_ws;                      // [0,256K): split W planes
    float* lgB = (float*)((char*)d_ws + 262144);   // [256K,+6.4M): partial logits

    hipLaunchKernelGGL(k0_prep, dim3(128), dim3(256), 0, stream, W1, wsW);
    hipLaunchKernelGGL(k1_mfma, dim3(((NRB + 7) / 8) * 16), dim3(K1_THREADS),
                       K1_LDS, stream, x, wsW, b1, W2, b2, lgA, lgB, N);
    hipLaunchKernelGGL(k2_seg, dim3(NSEG), dim3(256), 0, stream, bat, lgA, lgB, out, N);
    hipLaunchKernelGGL(k3_pool, dim3(NSEG), dim3(256), 0, stream, bat, x, Wt, bt, lgB, out, N);
}